// Round 7
// baseline (125.220 us; speedup 1.0000x reference)
//
#include <hip/hip_runtime.h>
#include <hip/hip_fp16.h>

// Ultimus: out = x + softmax((x@Kw+Kb)@(x@Qw+Qb)^T / sqrt(8)) @ (x@Vw+Vb) @ Zw + Zb
// N=8192, D_IN=48, D_ATTN=8, fp32 in/out.
//
// R18: ALL-F32 inner math. Evidence: R11/R13/R14/R16/R17 all land at 34-42us
// vs a ~10-12us 2cy-VALU model across three different broadcast mechanisms,
// and R17's forced inline-asm v_pk_fma_f16 changed NOTHING vs the builtin.
// Conclusion: packed-f16 VALU math runs at ~4-5cy/instr effective on gfx950
// (vector f16 peak == vector f32 peak per spec; R12's VALUBusy=33% of 66.8us
// = 22us busy for the 9M-pkfma stream confirms ~5cy). The f16 "2x packing"
// never existed. Rebuild scores+PV on v_fma_f32 (measured 2cy, m07):
//   per 2-j visit: 64 score fma + 64 PV fma + 16 cvt + 8 exp + 8 add ~384cy
//   x 4 waves/SIMD x 32 visits = ~20.5us VALU; LDS 6x b128/visit ~15us
//   (separate pipe). attn ~23-26us = at the f32-VALU roofline (2.15 GFLOP
//   at 103 TF = 21us). Beating THAT needs dot2/MFMA - next experiment.
// Numerics strictly improve (f32 scores/accum; f16 input quant unchanged).
//
//  - Bound-softmax (Cauchy-Schwarz row bound) => fixed per-row exponent
//    shift; partials over disjoint j-chunks combine by pure addition.
//  - QVJ per-j record (12 dwords = 48B): q[8] f32 | v[8] as 4 f16-pairs.
//    q read as 2x ds_read_b128 f32 (used 8x per row); v 1x b128 + 8 cvt
//    per j, reused across 4 rows.
//
// ws layout (floats):
//   [0, 32768)        Xksf16[8192] 8 f16/row (k * log2e/sqrt(8)), uint4/row
//   [32768, 131072)   QVJ[8192] 12 dwords/j: q f32 x8 | v f16-pair x4
//   [131072, 131328)  bmax[256] per-proj-block max ||q||^2
//   [131328, ...)     part[nch][8192][9] f32 partials: acc[0:8], l at [8]

#define QVJ_OFF  32768
#define BMAX_OFF 131072
#define PART_OFF 131328

typedef _Float16 hv2 __attribute__((ext_vector_type(2)));
union HVU { unsigned u; hv2 v; };

static __device__ __forceinline__ unsigned pku(float a, float b) {
    auto t = __builtin_amdgcn_cvt_pkrtz(a, b);
    union { decltype(t) x; unsigned u; } c; c.x = t; return c.u;
}
static __device__ __forceinline__ float loF(unsigned u) { HVU t; t.u = u; return (float)t.v.x; }
static __device__ __forceinline__ float hiF(unsigned u) { HVU t; t.u = u; return (float)t.v.y; }

__global__ __launch_bounds__(256) void proj_kernel(
    const float* __restrict__ x,
    const float* __restrict__ Kw, const float* __restrict__ Kb,
    const float* __restrict__ Qw, const float* __restrict__ Qb,
    const float* __restrict__ Vw, const float* __restrict__ Vb,
    unsigned* __restrict__ Xksf16, unsigned* __restrict__ QVJ,
    float* __restrict__ bmax)
{
    __shared__ float xs[32 * 49];     // +1 pad
    __shared__ float wAll[3 * 388];   // stride 388 (mod 32 = 4) spreads 3 mats
    __shared__ float bs[24];
    __shared__ float outv[32][25];    // 24 cols + pad
    const int tid = threadIdx.x;
    const int r0 = blockIdx.x * 32;

    for (int i = tid; i < 1536; i += 256) {
        int r = i / 48, c = i - r * 48;
        xs[r * 49 + c] = x[r0 * 48 + i];
    }
    for (int i = tid; i < 384; i += 256) {
        wAll[i]       = Kw[i];
        wAll[388 + i] = Qw[i];
        wAll[776 + i] = Vw[i];
    }
    if (tid < 8)       bs[tid] = Kb[tid];
    else if (tid < 16) bs[tid] = Qb[tid - 8];
    else if (tid < 24) bs[tid] = Vb[tid - 16];
    __syncthreads();

    const int rl = tid >> 3;
    const int g  = tid & 7;
    const int c0 = 3 * g;
    const float* xr = &xs[rl * 49];
    const float* w0 = &wAll[((c0 + 0) >> 3) * 388 + ((c0 + 0) & 7)];
    const float* w1 = &wAll[((c0 + 1) >> 3) * 388 + ((c0 + 1) & 7)];
    const float* w2 = &wAll[((c0 + 2) >> 3) * 388 + ((c0 + 2) & 7)];
    float a0 = bs[c0], a1 = bs[c0 + 1], a2 = bs[c0 + 2];
    #pragma unroll
    for (int k = 0; k < 48; k++) {
        const float xv = xr[k];
        a0 = fmaf(xv, w0[k * 8], a0);
        a1 = fmaf(xv, w1[k * 8], a1);
        a2 = fmaf(xv, w2[k * 8], a2);
    }
    outv[rl][c0] = a0; outv[rl][c0 + 1] = a1; outv[rl][c0 + 2] = a2;
    __syncthreads();

    // QVJ per-j record: 12 dwords = q f32[8] | v f16-pairs[4]
    for (int i = tid; i < 384; i += 256) {
        const int r = i / 12, f = i - r * 12;
        unsigned val;
        if (f < 8) {
            val = __float_as_uint(outv[r][8 + f]);            // q col f
        } else {
            const int pp = f - 8;
            val = pku(outv[r][16 + 2 * pp], outv[r][16 + 2 * pp + 1]);  // v pair
        }
        QVJ[((size_t)blockIdx.x * 32 + r) * 12 + f] = val;
    }
    const float kscale = 0.51008732149f;  // (1/sqrt(8)) * log2(e)
    if (tid < 32) {                       // K rows, f16 packed, pre-scaled
        uint4 o;
        o.x = pku(outv[tid][0] * kscale, outv[tid][1] * kscale);
        o.y = pku(outv[tid][2] * kscale, outv[tid][3] * kscale);
        o.z = pku(outv[tid][4] * kscale, outv[tid][5] * kscale);
        o.w = pku(outv[tid][6] * kscale, outv[tid][7] * kscale);
        ((uint4*)Xksf16)[r0 + tid] = o;
    }
    if (tid >= 192 && tid < 224) {        // block-max ||q||^2 (fp32)
        const int r = tid - 192;
        float n2 = 0.f;
        #pragma unroll
        for (int c = 0; c < 8; c++) n2 = fmaf(outv[r][8 + c], outv[r][8 + c], n2);
        #pragma unroll
        for (int off = 16; off > 0; off >>= 1)
            n2 = fmaxf(n2, __shfl_xor(n2, off, 64));
        if (r == 0) bmax[blockIdx.x] = n2;
    }
}

// grid = 32 row-groups (256 rows; 4 rows/lane) x nch j-chunks.
// Wave w handles j in [(chunk*4+w)*jpw, +jpw) in tiles of 64 j's.
// Per tile: block stages 4 waves x 64 j x 48B = 12KB into LDS (coalesced
// dwordx4), then per 2-j iteration: 6 uniform ds_read_b128 feed 4 rows x
// 2 j's of ALL-F32 score+exp+PV math (v_fma_f32 only, measured 2cy).
__global__ __launch_bounds__(256) void attn_kernel(
    const unsigned* __restrict__ Xksf16, const unsigned* __restrict__ QVJ,
    const float* __restrict__ bmax,
    float* __restrict__ part, int jpw)
{
    __shared__ float shf[4 * 256 * 9];   // 36,864B; slab (12KB) aliases front
    uint4*  slab4 = (uint4*)shf;
    float4* slabf = (float4*)shf;
    float*  redf  = shf;                 // red[w][r][c] = redf[(w*256+r)*9+c]

    const int tid  = threadIdx.x;
    const int lane = tid & 63;
    const int wv   = tid >> 6;
    const int rgrp  = blockIdx.x & 31;
    const int chunk = blockIdx.x >> 5;

    // qmax2 = max over 256 per-proj-block maxima
    float m = fmaxf(fmaxf(bmax[lane], bmax[64 + lane]),
                    fmaxf(bmax[128 + lane], bmax[192 + lane]));
    #pragma unroll
    for (int off = 32; off > 0; off >>= 1)
        m = fmaxf(m, __shfl_xor(m, off, 64));
    const float qmax2 = m;

    // 4 K-rows per lane as f32 (cvt once); rows rgrp*256 + i*64 + lane
    float kf[4][8];
    float sinit[4], l[4], acc[4][8];
    #pragma unroll
    for (int i = 0; i < 4; ++i) {
        const uint4 kv = ((const uint4*)Xksf16)[rgrp * 256 + i * 64 + lane];
        kf[i][0] = loF(kv.x); kf[i][1] = hiF(kv.x);
        kf[i][2] = loF(kv.y); kf[i][3] = hiF(kv.y);
        kf[i][4] = loF(kv.z); kf[i][5] = hiF(kv.z);
        kf[i][6] = loF(kv.w); kf[i][7] = hiF(kv.w);
        float kn2 = 0.f;
        #pragma unroll
        for (int c = 0; c < 8; c++) kn2 = fmaf(kf[i][c], kf[i][c], kn2);
        sinit[i] = -sqrtf(kn2 * qmax2);   // s' = sinit + k.q <= 0: p in (0,1]
        l[i] = 0.f;
        #pragma unroll
        for (int c = 0; c < 8; c++) acc[i][c] = 0.f;
    }

    const uint4* QVJ4 = (const uint4*)QVJ;
    const int nt = jpw >> 6;             // jpw is a multiple of 64

    for (int t = 0; t < nt; ++t) {
        // stage: wave w's 64-j tile -> slab[w*192 .. w*192+192) (uint4 units)
        for (int i = tid; i < 768; i += 256) {
            const int w = i / 192, rec = i - w * 192;
            slab4[i] = QVJ4[((size_t)(chunk * 4 + w) * jpw + t * 64) * 3 + rec];
        }
        __syncthreads();

        const int wbase = wv * 192;
        #pragma unroll 1
        for (int jj = 0; jj < 32; ++jj) {
            const int b = wbase + jj * 6;
            const float4 qa0 = slabf[b + 0];   // jA: q0..3
            const float4 qa1 = slabf[b + 1];   // jA: q4..7
            const uint4  va  = slab4[b + 2];   // jA: v f16-pairs
            const float4 qb0 = slabf[b + 3];   // jB: q0..3
            const float4 qb1 = slabf[b + 4];   // jB: q4..7
            const uint4  vb  = slab4[b + 5];   // jB: v f16-pairs
            const float vA0 = loF(va.x), vA1 = hiF(va.x), vA2 = loF(va.y), vA3 = hiF(va.y);
            const float vA4 = loF(va.z), vA5 = hiF(va.z), vA6 = loF(va.w), vA7 = hiF(va.w);
            const float vB0 = loF(vb.x), vB1 = hiF(vb.x), vB2 = loF(vb.y), vB3 = hiF(vb.y);
            const float vB4 = loF(vb.z), vB5 = hiF(vb.z), vB6 = loF(vb.w), vB7 = hiF(vb.w);
            #pragma unroll
            for (int i = 0; i < 4; ++i) {
                float sA = sinit[i];
                sA = fmaf(kf[i][0], qa0.x, sA);
                sA = fmaf(kf[i][1], qa0.y, sA);
                sA = fmaf(kf[i][2], qa0.z, sA);
                sA = fmaf(kf[i][3], qa0.w, sA);
                sA = fmaf(kf[i][4], qa1.x, sA);
                sA = fmaf(kf[i][5], qa1.y, sA);
                sA = fmaf(kf[i][6], qa1.z, sA);
                sA = fmaf(kf[i][7], qa1.w, sA);
                float sB = sinit[i];
                sB = fmaf(kf[i][0], qb0.x, sB);
                sB = fmaf(kf[i][1], qb0.y, sB);
                sB = fmaf(kf[i][2], qb0.z, sB);
                sB = fmaf(kf[i][3], qb0.w, sB);
                sB = fmaf(kf[i][4], qb1.x, sB);
                sB = fmaf(kf[i][5], qb1.y, sB);
                sB = fmaf(kf[i][6], qb1.z, sB);
                sB = fmaf(kf[i][7], qb1.w, sB);
                const float pA = __builtin_amdgcn_exp2f(sA);
                const float pB = __builtin_amdgcn_exp2f(sB);
                l[i] += pA + pB;
                acc[i][0] = fmaf(pA, vA0, fmaf(pB, vB0, acc[i][0]));
                acc[i][1] = fmaf(pA, vA1, fmaf(pB, vB1, acc[i][1]));
                acc[i][2] = fmaf(pA, vA2, fmaf(pB, vB2, acc[i][2]));
                acc[i][3] = fmaf(pA, vA3, fmaf(pB, vB3, acc[i][3]));
                acc[i][4] = fmaf(pA, vA4, fmaf(pB, vB4, acc[i][4]));
                acc[i][5] = fmaf(pA, vA5, fmaf(pB, vB5, acc[i][5]));
                acc[i][6] = fmaf(pA, vA6, fmaf(pB, vB6, acc[i][6]));
                acc[i][7] = fmaf(pA, vA7, fmaf(pB, vB7, acc[i][7]));
            }
        }
        __syncthreads();   // all waves done reading slab before reuse
    }

    // merge the block's 4 waves via LDS (redf aliases the slab)
    #pragma unroll
    for (int i = 0; i < 4; ++i) {
        const int r = i * 64 + lane;
        #pragma unroll
        for (int c = 0; c < 8; c++)
            redf[(wv * 256 + r) * 9 + c] = acc[i][c];
        redf[(wv * 256 + r) * 9 + 8] = l[i];
    }
    __syncthreads();
    for (int e = tid; e < 2304; e += 256) {
        const int r = e / 9, c = e - r * 9;
        const float s = redf[(0 * 256 + r) * 9 + c] + redf[(1 * 256 + r) * 9 + c]
                      + redf[(2 * 256 + r) * 9 + c] + redf[(3 * 256 + r) * 9 + c];
        part[((size_t)chunk * 8192 + rgrp * 256 + r) * 9 + c] = s;
    }
}

// 256 blocks x 32 rows; reduction parallelized over all 256 threads
// (thread = (row, col)), so nch=32 partial sets stay cheap.
__global__ __launch_bounds__(256) void finish_kernel(
    const float* __restrict__ x,
    const float* __restrict__ Zw, const float* __restrict__ Zb,
    const float* __restrict__ part, float* __restrict__ out, int nch)
{
    __shared__ float Zs[32 * 9];
    __shared__ float Zl[32];
    __shared__ float zw_s[384];
    __shared__ float zb_s[48];
    const int tid = threadIdx.x;
    const int r0 = blockIdx.x * 32;

    for (int i = tid; i < 384; i += 256) zw_s[i] = Zw[i];
    if (tid < 48) zb_s[tid] = Zb[tid];

    // phase 1: thread = (row r = tid>>3, col c = tid&7); c==0 also sums l
    {
        const int r = tid >> 3, c = tid & 7;
        float a = 0.f, l = 0.f;
        #pragma unroll 4
        for (int ch = 0; ch < nch; ch++) {
            const float* p = part + ((size_t)ch * 8192 + r0 + r) * 9;
            a += p[c];
            if (c == 0) l += p[8];
        }
        if (c == 0) Zl[r] = l;
        __syncthreads();
        Zs[r * 9 + c] = a * (1.0f / Zl[r]);
    }
    __syncthreads();

    for (int e = tid; e < 32 * 48; e += 256) {
        const int r = e / 48, c = e - r * 48;
        float o = x[r0 * 48 + e] + zb_s[c];
        #pragma unroll
        for (int k = 0; k < 8; k++) o = fmaf(Zs[r * 9 + k], zw_s[k * 48 + c], o);
        out[r0 * 48 + e] = o;
    }
}

extern "C" void kernel_launch(void* const* d_in, const int* in_sizes, int n_in,
                              void* d_out, int out_size, void* d_ws, size_t ws_size,
                              hipStream_t stream) {
    const float* x  = (const float*)d_in[0];
    const float* Kw = (const float*)d_in[1];
    const float* Kb = (const float*)d_in[2];
    const float* Qw = (const float*)d_in[3];
    const float* Qb = (const float*)d_in[4];
    const float* Vw = (const float*)d_in[5];
    const float* Vb = (const float*)d_in[6];
    const float* Zw = (const float*)d_in[7];
    const float* Zb = (const float*)d_in[8];
    float* out = (float*)d_out;

    float* ws = (float*)d_ws;
    unsigned* Xksf16 = (unsigned*)ws;
    unsigned* QVJ    = (unsigned*)(ws + QVJ_OFF);
    float* bmax      = ws + BMAX_OFF;
    float* part      = ws + PART_OFF;

    int nch = 32;
    const size_t avail = ws_size / 4;
    while (nch > 1 && (size_t)PART_OFF + (size_t)nch * 8192 * 9 > avail) nch >>= 1;
    const int jpw = 2048 / nch;   // j's per wave (8192 j / (nch*4 waves))

    proj_kernel<<<256, 256, 0, stream>>>(x, Kw, Kb, Qw, Qb, Vw, Vb,
                                         Xksf16, QVJ, bmax);
    attn_kernel<<<32 * nch, 256, 0, stream>>>(Xksf16, QVJ, bmax, part, jpw);
    finish_kernel<<<256, 256, 0, stream>>>(x, Zw, Zb, part, out, nch);
}

// Round 8
// 111.260 us; speedup vs baseline: 1.1255x; 1.1255x over previous
//
#include <hip/hip_runtime.h>
#include <hip/hip_fp16.h>

// Ultimus: out = x + softmax((x@Kw+Kb)@(x@Qw+Qb)^T / sqrt(8)) @ (x@Vw+Vb) @ Zw + Zb
// N=8192, D_IN=48, D_ATTN=8, fp32 in/out.
//
// R19: MFMA rewrite of attn. R18's counters: attn 41.8us, VALUBusy 64-71%,
// MfmaUtil 0.0 -> the VALU is the wall (elementwise floor ~16-20us even at
// 100% issue) while the matrix pipe idles on matmul-shaped work. Both
// matmuls -> v_mfma_f32_32x32x16_f16 (D=8 padded to K=16):
//  - scores: S^T tile = mfma(A=Q', B=K'): bias folded into the pad slots
//    (K' k=8 slot = sinit_r, Q' k=8 slot = 1.0) so C = k.q + sinit directly
//    (pre-scaled by log2e/sqrt8). exp2 on the 16 C regs -> P (f32).
//  - PV: D[c][r] = sum_j V^T[c][j] P^T[j][r]: A = V'^T gathered with a
//    j-PERMUTATION chosen to match the C-layout reg order, so the P^T
//    B-fragments are just 8 cvt_pkrtz of consecutive C regs - ZERO
//    cross-lane moves. Ones-row c=8 of V'^T makes the softmax denominator
//    a free 9th output row. C accumulates over j-tiles (f32).
// Per wave: 32 rows x 256 j, 8 tiles, no LDS, no barriers, waves indep.
// Model: ~400 VALU/wave x 8192 waves ~5us + exp 3.4us + MFMA 0.6us ->
// attn ~7-12us (vs 41.8). Declared risk: A/B frag k-map = (lane>>5)*8+elem
// (analog of m162-verified 16x16 layout); harness check catches if wrong.
//
// ws layout (dwords/floats):
//   [0, 32768)        Xksf16[8192] 8 f16/row (k * log2e/sqrt(8)), uint4/row
//   [32768, 65536)    Qf16[8192]   8 f16/row (raw q), uint4/row
//   [65536, 102400)   Vt[9][8192]  f16, row-major; row 8 = 1.0 (denominator)
//   [102400, 110592)  kn2[8192]    f32 ||k_scaled||^2
//   [110592, 110848)  bmax[256]    per-proj-block max ||q||^2
//   [110848, ...)     part[nch][8192][9] f32 partials: acc[0:8], l at [8]

#define XKS_OFF  0
#define Q4_OFF   32768
#define VT_OFF   65536
#define KN2_OFF  102400
#define BMAX_OFF 110592
#define PART_OFF 110848

typedef _Float16 half8 __attribute__((ext_vector_type(8)));
typedef float f32x16 __attribute__((ext_vector_type(16)));
union U8 { unsigned u[4]; half8 h; };

static __device__ __forceinline__ unsigned pku(float a, float b) {
    auto t = __builtin_amdgcn_cvt_pkrtz(a, b);
    union { decltype(t) x; unsigned u; } c; c.x = t; return c.u;
}

__global__ __launch_bounds__(256) void proj_kernel(
    const float* __restrict__ x,
    const float* __restrict__ Kw, const float* __restrict__ Kb,
    const float* __restrict__ Qw, const float* __restrict__ Qb,
    const float* __restrict__ Vw, const float* __restrict__ Vb,
    unsigned* __restrict__ Xksf16, unsigned* __restrict__ Q4,
    unsigned* __restrict__ Vt, float* __restrict__ kn2,
    float* __restrict__ bmax)
{
    __shared__ float xs[32 * 49];     // +1 pad
    __shared__ float wAll[3 * 388];   // stride 388 (mod 32 = 4) spreads 3 mats
    __shared__ float bs[24];
    __shared__ float outv[32][25];    // 24 cols + pad
    const int tid = threadIdx.x;
    const int r0 = blockIdx.x * 32;

    for (int i = tid; i < 1536; i += 256) {
        int r = i / 48, c = i - r * 48;
        xs[r * 49 + c] = x[r0 * 48 + i];
    }
    for (int i = tid; i < 384; i += 256) {
        wAll[i]       = Kw[i];
        wAll[388 + i] = Qw[i];
        wAll[776 + i] = Vw[i];
    }
    if (tid < 8)       bs[tid] = Kb[tid];
    else if (tid < 16) bs[tid] = Qb[tid - 8];
    else if (tid < 24) bs[tid] = Vb[tid - 16];
    __syncthreads();

    const int rl = tid >> 3;
    const int g  = tid & 7;
    const int c0 = 3 * g;
    const float* xr = &xs[rl * 49];
    const float* w0 = &wAll[((c0 + 0) >> 3) * 388 + ((c0 + 0) & 7)];
    const float* w1 = &wAll[((c0 + 1) >> 3) * 388 + ((c0 + 1) & 7)];
    const float* w2 = &wAll[((c0 + 2) >> 3) * 388 + ((c0 + 2) & 7)];
    float a0 = bs[c0], a1 = bs[c0 + 1], a2 = bs[c0 + 2];
    #pragma unroll
    for (int k = 0; k < 48; k++) {
        const float xv = xr[k];
        a0 = fmaf(xv, w0[k * 8], a0);
        a1 = fmaf(xv, w1[k * 8], a1);
        a2 = fmaf(xv, w2[k * 8], a2);
    }
    outv[rl][c0] = a0; outv[rl][c0 + 1] = a1; outv[rl][c0 + 2] = a2;
    __syncthreads();

    const float kscale = 0.51008732149f;  // (1/sqrt(8)) * log2(e)
    if (tid < 32) {                       // K rows, f16 packed, pre-scaled
        uint4 o;
        o.x = pku(outv[tid][0] * kscale, outv[tid][1] * kscale);
        o.y = pku(outv[tid][2] * kscale, outv[tid][3] * kscale);
        o.z = pku(outv[tid][4] * kscale, outv[tid][5] * kscale);
        o.w = pku(outv[tid][6] * kscale, outv[tid][7] * kscale);
        ((uint4*)Xksf16)[r0 + tid] = o;
    } else if (tid < 64) {                // Q rows, f16 packed, raw
        const int r = tid - 32;
        uint4 o;
        o.x = pku(outv[r][8],  outv[r][9]);
        o.y = pku(outv[r][10], outv[r][11]);
        o.z = pku(outv[r][12], outv[r][13]);
        o.w = pku(outv[r][14], outv[r][15]);
        ((uint4*)Q4)[r0 + r] = o;
    } else if (tid < 192) {               // Vt[c][j] f16 pairs
        const int i = tid - 64;
        const int c = i >> 4, t = i & 15;
        Vt[c * 4096 + blockIdx.x * 16 + t] =
            pku(outv[2 * t][16 + c], outv[2 * t + 1][16 + c]);
    } else if (tid < 224) {               // block-max ||q||^2 (fp32)
        const int r = tid - 192;
        float n2 = 0.f;
        #pragma unroll
        for (int c = 0; c < 8; c++) n2 = fmaf(outv[r][8 + c], outv[r][8 + c], n2);
        #pragma unroll
        for (int off = 16; off > 0; off >>= 1)
            n2 = fmaxf(n2, __shfl_xor(n2, off, 64));
        if (r == 0) bmax[blockIdx.x] = n2;
    } else {                              // kn2 = ||k_scaled||^2
        const int r = tid - 224;
        float s = 0.f;
        #pragma unroll
        for (int c = 0; c < 8; c++) { const float v = outv[r][c]; s = fmaf(v, v, s); }
        kn2[r0 + r] = s * (kscale * kscale);
    }
    if (tid < 16)                          // ones row c=8 of Vt (denominator)
        Vt[8 * 4096 + blockIdx.x * 16 + tid] = 0x3C003C00u;
}

// wave = (rg, ch): 32 rows x (8192/nch) j, ntiles 32-j tiles. No LDS/barriers.
// Per tile: 1 score MFMA (S^T, bias in pad slot) -> 16 exp2 -> 8 cvt_pk ->
// 2 PV MFMA accumulating f32. wid = ch*256 + rg so a block's 4 waves share
// the ch's Q/V tiles via L1.
__global__ __launch_bounds__(256) void attn_kernel(
    const uint4* __restrict__ Xks4, const uint4* __restrict__ Q4,
    const unsigned* __restrict__ Vt, const float* __restrict__ kn2,
    const float* __restrict__ bmax, float* __restrict__ part, int ntiles)
{
    const int tid  = threadIdx.x;
    const int lane = tid & 63;
    const int wv   = tid >> 6;
    const int wid  = blockIdx.x * 4 + wv;
    const int rg = wid & 255, ch = wid >> 8;
    const int h = lane >> 5, hl = lane & 31;
    const int rbase = rg * 32;
    const int j0base = ch * (ntiles * 32);

    // qmax2 = max over 256 per-proj-block maxima
    float m = fmaxf(fmaxf(bmax[lane], bmax[64 + lane]),
                    fmaxf(bmax[128 + lane], bmax[192 + lane]));
    #pragma unroll
    for (int off = 32; off > 0; off >>= 1)
        m = fmaxf(m, __shfl_xor(m, off, 64));
    const float qmax2 = m;

    // B-frag = K': lanes<32 hold k0..7 of row rbase+hl; lanes>=32 hold
    // (sinit, 0,...) in k8..15 (bias slot).
    U8 Bk;
    if (h == 0) {
        const uint4 kv = Xks4[rbase + hl];
        Bk.u[0] = kv.x; Bk.u[1] = kv.y; Bk.u[2] = kv.z; Bk.u[3] = kv.w;
    } else {
        const float sinit = -sqrtf(kn2[rbase + hl] * qmax2);
        Bk.u[0] = pku(sinit, 0.f); Bk.u[1] = 0u; Bk.u[2] = 0u; Bk.u[3] = 0u;
    }

    const f32x16 zc = {0.f,0.f,0.f,0.f,0.f,0.f,0.f,0.f,
                       0.f,0.f,0.f,0.f,0.f,0.f,0.f,0.f};
    f32x16 acc = {0.f,0.f,0.f,0.f,0.f,0.f,0.f,0.f,
                  0.f,0.f,0.f,0.f,0.f,0.f,0.f,0.f};

    const int cva = hl;                  // V^T row (c) carried by this lane
    const bool vv = (cva < 9);
    const uint2* V2 = (const uint2*)Vt;  // 4 f16 per uint2

    for (int t = 0; t < ntiles; ++t) {
        const int j0 = j0base + t * 32;

        // A-frag = Q': lanes<32 hold q0..7 of col j0+hl; lanes>=32 hold 1.0
        // in the k8 bias slot.
        U8 Aq;
        if (h == 0) {
            const uint4 qv = Q4[j0 + hl];
            Aq.u[0] = qv.x; Aq.u[1] = qv.y; Aq.u[2] = qv.z; Aq.u[3] = qv.w;
        } else {
            Aq.u[0] = 0x00003C00u; Aq.u[1] = 0u; Aq.u[2] = 0u; Aq.u[3] = 0u;
        }
        // S^T tile: lane holds col r=rbase+hl; regs = 16 j's
        const f32x16 s = __builtin_amdgcn_mfma_f32_32x32x16_f16(Aq.h, Bk.h, zc, 0, 0, 0);

        const unsigned pk01 = pku(__builtin_amdgcn_exp2f(s[0]),  __builtin_amdgcn_exp2f(s[1]));
        const unsigned pk23 = pku(__builtin_amdgcn_exp2f(s[2]),  __builtin_amdgcn_exp2f(s[3]));
        const unsigned pk45 = pku(__builtin_amdgcn_exp2f(s[4]),  __builtin_amdgcn_exp2f(s[5]));
        const unsigned pk67 = pku(__builtin_amdgcn_exp2f(s[6]),  __builtin_amdgcn_exp2f(s[7]));
        const unsigned pk89 = pku(__builtin_amdgcn_exp2f(s[8]),  __builtin_amdgcn_exp2f(s[9]));
        const unsigned pkAB = pku(__builtin_amdgcn_exp2f(s[10]), __builtin_amdgcn_exp2f(s[11]));
        const unsigned pkCD = pku(__builtin_amdgcn_exp2f(s[12]), __builtin_amdgcn_exp2f(s[13]));
        const unsigned pkEF = pku(__builtin_amdgcn_exp2f(s[14]), __builtin_amdgcn_exp2f(s[15]));

        // V'^T A-frags, j-permuted to match the C-layout reg order:
        // lane's k-slot s -> j' = (s&3) + 8*((s>>2)&1) + 4*h (+16 for tile 2)
        uint2 va0 = {0u,0u}, va1 = {0u,0u}, va2 = {0u,0u}, va3 = {0u,0u};
        if (vv) {
            const int vb = cva * 8192 + j0 + 4 * h;
            va0 = V2[(vb)      >> 2];   // j' 0..3   (+4h)
            va1 = V2[(vb + 8)  >> 2];   // j' 8..11  (+4h)
            va2 = V2[(vb + 16) >> 2];   // j' 16..19 (+4h)
            va3 = V2[(vb + 24) >> 2];   // j' 24..27 (+4h)
        }
        U8 A2a; A2a.u[0] = va0.x; A2a.u[1] = va0.y; A2a.u[2] = va1.x; A2a.u[3] = va1.y;
        U8 B2a; B2a.u[0] = pk01;  B2a.u[1] = pk23;  B2a.u[2] = pk45;  B2a.u[3] = pk67;
        acc = __builtin_amdgcn_mfma_f32_32x32x16_f16(A2a.h, B2a.h, acc, 0, 0, 0);
        U8 A2b; A2b.u[0] = va2.x; A2b.u[1] = va2.y; A2b.u[2] = va3.x; A2b.u[3] = va3.y;
        U8 B2b; B2b.u[0] = pk89;  B2b.u[1] = pkAB;  B2b.u[2] = pkCD;  B2b.u[3] = pkEF;
        acc = __builtin_amdgcn_mfma_f32_32x32x16_f16(A2b.h, B2b.h, acc, 0, 0, 0);
    }

    // acc reg R -> out[c=(R&3)+8*(R>>2)+4h][r=rbase+hl]; valid c<=8.
    float* pr = part + ((size_t)ch * 8192 + rbase + hl) * 9;
    if (h == 0) {
        pr[0] = acc[0]; pr[1] = acc[1]; pr[2] = acc[2]; pr[3] = acc[3];
        pr[8] = acc[4];                  // c=8 = ones row = denominator l
    } else {
        pr[4] = acc[0]; pr[5] = acc[1]; pr[6] = acc[2]; pr[7] = acc[3];
    }
}

// 256 blocks x 32 rows; reduction parallelized over all 256 threads
// (thread = (row, col)), so nch=32 partial sets stay cheap.
__global__ __launch_bounds__(256) void finish_kernel(
    const float* __restrict__ x,
    const float* __restrict__ Zw, const float* __restrict__ Zb,
    const float* __restrict__ part, float* __restrict__ out, int nch)
{
    __shared__ float Zs[32 * 9];
    __shared__ float Zl[32];
    __shared__ float zw_s[384];
    __shared__ float zb_s[48];
    const int tid = threadIdx.x;
    const int r0 = blockIdx.x * 32;

    for (int i = tid; i < 384; i += 256) zw_s[i] = Zw[i];
    if (tid < 48) zb_s[tid] = Zb[tid];

    // phase 1: thread = (row r = tid>>3, col c = tid&7); c==0 also sums l
    {
        const int r = tid >> 3, c = tid & 7;
        float a = 0.f, l = 0.f;
        #pragma unroll 4
        for (int ch = 0; ch < nch; ch++) {
            const float* p = part + ((size_t)ch * 8192 + r0 + r) * 9;
            a += p[c];
            if (c == 0) l += p[8];
        }
        if (c == 0) Zl[r] = l;
        __syncthreads();
        Zs[r * 9 + c] = a * (1.0f / Zl[r]);
    }
    __syncthreads();

    for (int e = tid; e < 32 * 48; e += 256) {
        const int r = e / 48, c = e - r * 48;
        float o = x[r0 * 48 + e] + zb_s[c];
        #pragma unroll
        for (int k = 0; k < 8; k++) o = fmaf(Zs[r * 9 + k], zw_s[k * 48 + c], o);
        out[r0 * 48 + e] = o;
    }
}

extern "C" void kernel_launch(void* const* d_in, const int* in_sizes, int n_in,
                              void* d_out, int out_size, void* d_ws, size_t ws_size,
                              hipStream_t stream) {
    const float* x  = (const float*)d_in[0];
    const float* Kw = (const float*)d_in[1];
    const float* Kb = (const float*)d_in[2];
    const float* Qw = (const float*)d_in[3];
    const float* Qb = (const float*)d_in[4];
    const float* Vw = (const float*)d_in[5];
    const float* Vb = (const float*)d_in[6];
    const float* Zw = (const float*)d_in[7];
    const float* Zb = (const float*)d_in[8];
    float* out = (float*)d_out;

    float* ws = (float*)d_ws;
    unsigned* Xksf16 = (unsigned*)(ws + XKS_OFF);
    unsigned* Q4     = (unsigned*)(ws + Q4_OFF);
    unsigned* Vt     = (unsigned*)(ws + VT_OFF);
    float* kn2       = ws + KN2_OFF;
    float* bmax      = ws + BMAX_OFF;
    float* part      = ws + PART_OFF;

    int nch = 32;
    const size_t avail = ws_size / 4;
    while (nch > 1 && (size_t)PART_OFF + (size_t)nch * 8192 * 9 > avail) nch >>= 1;
    const int ntiles = 256 / nch;   // 32-j tiles per wave (8192 j / (nch*32))

    proj_kernel<<<256, 256, 0, stream>>>(x, Kw, Kb, Qw, Qb, Vw, Vb,
                                         Xksf16, Q4, Vt, kn2, bmax);
    attn_kernel<<<64 * nch, 256, 0, stream>>>((const uint4*)Xksf16,
                                              (const uint4*)Q4, Vt, kn2,
                                              bmax, part, ntiles);
    finish_kernel<<<256, 256, 0, stream>>>(x, Zw, Zb, part, out, nch);
}